// Round 16
// baseline (355.809 us; speedup 1.0000x reference)
//
#include <hip/hip_runtime.h>

#define N_NODESC 10000
#define N_EDGESC 160000
#define NBLK_TOT 2500                 // N_EDGESC/64
#define NP       (N_NODESC*128)       // plane size (floats)
#define INV128   0.08838834764831845f // 1/sqrt(128)
#define INV_SQRT3C 0.5773502691896258f
#define SCALE_OUT 0.00390625f         // (1/sqrt(256))/16

typedef __attribute__((ext_vector_type(8))) short bf16x8;
typedef __attribute__((ext_vector_type(4))) float f32x4;

__device__ __forceinline__ float silu_f(float x) {
  return x / (1.f + __expf(-x));
}
__device__ __forceinline__ ushort f2bf_rne(float x) {
  uint u = __float_as_uint(x);
  uint r = (u + 0x7FFFu + ((u >> 16) & 1u)) >> 16;
  return (ushort)r;
}
__device__ __forceinline__ float bf2f(ushort h) {
  return __uint_as_float(((uint)h) << 16);
}

// ---------------- merged: edge histogram + weight prep ---------------------
__global__ __launch_bounds__(256) void k_histprep(
    const int* __restrict__ eidx, int* __restrict__ deg,
    const float* __restrict__ W2, const float* __restrict__ W3,
    const float* __restrict__ Wu0, const float* __restrict__ Wu1,
    const float* __restrict__ Wo0, const float* __restrict__ Wo1,
    ushort* __restrict__ TT) {
  const int bid = blockIdx.x;
  if (bid < 625) {
    int e = bid * 256 + threadIdx.x;
    if (e < N_EDGESC) atomicAdd(&deg[eidx[N_EDGESC + e]], 1);
    return;
  }
  int id = (bid - 625) * 256 + threadIdx.x;
  if (id < 16384) {                   // W2
    int k = id >> 7, n = id & 127;
    float v = W2[k * 128 + n];
    ushort hi = f2bf_rne(v);
    TT[4 * 16384 + n * 128 + k] = hi;
    TT[5 * 16384 + n * 128 + k] = f2bf_rne(v - bf2f(hi));
  } else if (id < 81920) {            // W3 hi only
    int s = id - 16384;
    int k = s >> 9, col = s & 511;
    int cb = col >> 7, n = col & 127;
    TT[(6 + cb) * 16384 + n * 128 + k] = f2bf_rne(W3[k * 512 + col]);
  } else if (id < 114688) {           // Wu0 (t10/11), Wu1 (t12/13)
    int t = id - 81920;
    int w = t >> 14, r = t & 16383;
    int k = r >> 7, n = r & 127;
    const float* W = w ? Wu1 : Wu0;
    float v = W[k * 128 + n];
    ushort hi = f2bf_rne(v);
    TT[(10 + w * 2) * 16384 + n * 128 + k] = hi;
    TT[(11 + w * 2) * 16384 + n * 128 + k] = f2bf_rne(v - bf2f(hi));
  } else if (id < 180224) {           // Wo0/Wo1 -> t16..23
    int t = id - 114688;
    int w = t >> 15, r = t & 32767;
    int k = r >> 7, n = r & 127;
    const float* W = w ? Wo1 : Wo0;
    float v = W[k * 128 + n];
    int kh = k >> 7, kk = k & 127;
    ushort hi = f2bf_rne(v);
    TT[(16 + w * 4 + kh * 2) * 16384 + n * 128 + kk] = hi;
    TT[(17 + w * 4 + kh * 2) * 16384 + n * 128 + kk] = f2bf_rne(v - bf2f(hi));
  }
}

__global__ __launch_bounds__(1024) void k_scan(const int* __restrict__ deg,
                                               int* __restrict__ row_start,
                                               int* __restrict__ cursor) {
  __shared__ int buf[1024];
  const int t = threadIdx.x;
  for (int i = t; i < N_NODESC; i += 1024) cursor[i] = 0;
  int d[10];
  int loc = 0;
  #pragma unroll
  for (int i = 0; i < 10; i++) {
    int n = t * 10 + i;
    d[i] = (n < N_NODESC) ? deg[n] : 0;
    loc += d[i];
  }
  buf[t] = loc;
  __syncthreads();
  int v = loc;
  for (int off = 1; off < 1024; off <<= 1) {
    int u = (t >= off) ? buf[t - off] : 0;
    __syncthreads();
    v += u;
    buf[t] = v;
    __syncthreads();
  }
  int run = v - loc;
  #pragma unroll
  for (int i = 0; i < 10; i++) {
    int n = t * 10 + i;
    if (n < N_NODESC) row_start[n] = run;
    run += d[i];
  }
  if (t == 1023) row_start[N_NODESC] = v;
}

__global__ __launch_bounds__(256) void k_scatter(const int* __restrict__ eidx,
                                                 const int* __restrict__ row_start,
                                                 int* __restrict__ cursor,
                                                 int* __restrict__ perm) {
  int e = blockIdx.x * 256 + threadIdx.x;
  if (e < N_EDGESC) {
    int r = eidx[N_EDGESC + e];
    int pos = row_start[r] + atomicAdd(&cursor[r], 1);
    perm[pos] = e;
  }
}

// ---------------- weight compose: TT[t0..3] = bf16(Wsc @ W1block) ----------
__global__ __launch_bounds__(256) void k_wcomp(
    const float* __restrict__ Wsc, const float* __restrict__ W1,
    ushort* __restrict__ TT) {
  __shared__ float sA2[64][132];
  __shared__ float sW2[128][128];
  const int rh = blockIdx.x;   // output row half (0/1)
  const int wb = blockIdx.y;   // which W1 block (0: rows 0-127, 1: 128-255)
  for (int idx = threadIdx.x; idx < 128 * 32; idx += 256) {
    int k = idx >> 5, fc = (idx & 31) << 2;
    *(float4*)&sW2[k][fc] = *(const float4*)&W1[(wb * 128 + k) * 128 + fc];
  }
  for (int idx = threadIdx.x; idx < 64 * 32; idx += 256) {
    int i = idx >> 5, fc = (idx & 31) << 2;
    *(float4*)&sA2[i][fc] = *(const float4*)&Wsc[(rh * 64 + i) * 128 + fc];
  }
  __syncthreads();
  const int r0 = (threadIdx.x >> 4) * 4;
  const int c0 = (threadIdx.x & 15) * 8;
  float acc[4][8] = {};
  #pragma unroll 4
  for (int k = 0; k < 128; k++) {
    float a[4];
    #pragma unroll
    for (int j = 0; j < 4; j++) a[j] = sA2[r0 + j][k];
    float w[8];
    *(float4*)&w[0] = *(const float4*)&sW2[k][c0];
    *(float4*)&w[4] = *(const float4*)&sW2[k][c0 + 4];
    #pragma unroll
    for (int j = 0; j < 4; j++)
      #pragma unroll
      for (int c = 0; c < 8; c++) acc[j][c] += a[j] * w[c];
  }
  #pragma unroll
  for (int j = 0; j < 4; j++) {
    int u = rh * 64 + r0 + j;    // input-feature index (k of B-tile)
    #pragma unroll
    for (int c = 0; c < 8; c++) {
      float v = acc[j][c];
      ushort hi = f2bf_rne(v);
      TT[(wb * 2 + 0) * 16384 + (c0 + c) * 128 + u] = hi;
      TT[(wb * 2 + 1) * 16384 + (c0 + c) * 128 + u] = f2bf_rne(v - bf2f(hi));
    }
  }
}

// ---------------- shared GEMM macro (A 1-term, full-K tile) ----------------
#define GEMM_PASS1(ACC)                                                        \
  _Pragma("unroll") for (int s = 0; s < 4; s++) {                              \
    bf16x8 ah = *(const bf16x8*)&sAh[ar][s * 32 + lq * 8];                     \
    _Pragma("unroll") for (int nt = 0; nt < 8; nt++) {                         \
      bf16x8 bb = *(const bf16x8*)&sB[nt * 16 + ln][s * 32 + lq * 8];          \
      ACC[nt] = __builtin_amdgcn_mfma_f32_16x16x32_bf16(ah, bb, ACC[nt], 0, 0, 0); \
    }                                                                          \
  }

// transient staging: load whole tile to short-lived regs, write to LDS
#define STAGEB(T) { uint4 tv[8];                                               \
  _Pragma("unroll") for (int i = 0; i < 8; i++)                                \
    tv[i] = ttp[(T) * 2048 + cid + 256 * i];                                   \
  _Pragma("unroll") for (int i = 0; i < 8; i++) {                              \
    int c = cid + 256 * i;                                                     \
    *(uint4*)&sB[c >> 4][(c & 15) * 8] = tv[i]; } }

// ---------------- K1: node up-projections (MFMA, A 1-term, 3 blk/CU) -------
__global__ __launch_bounds__(256, 3) void k_node_up(
    const float* __restrict__ nf,
    const ushort* __restrict__ TT,
    float* __restrict__ P1s,
    float* __restrict__ P1r,
    float* __restrict__ SU,
    float* __restrict__ VU,
    int* __restrict__ perm,
    const int* __restrict__ row_start)
{
  __shared__ ushort sAh[64][132];
  __shared__ ushort sB[128][132];
  const int n0 = blockIdx.x * 64;
  const int which = blockIdx.y;
  const int cid = threadIdx.x;
  const int wid = cid >> 6;
  const int lane = cid & 63;
  const int lq = lane >> 4;
  const int ln = lane & 15;
  const int ar = wid * 16 + ln;
  const uint4* ttp = (const uint4*)TT;

  if (which == 4) {
    // fused sortseg: deterministic ascending edge-id order per node
    int n = blockIdx.x * 256 + cid;
    if (n < N_NODESC) {
      int s = row_start[n], e = row_start[n + 1];
      for (int i = s + 1; i < e; i++) {
        int key = perm[i];
        int j = i - 1;
        while (j >= s && perm[j] > key) { perm[j + 1] = perm[j]; j--; }
        perm[j + 1] = key;
      }
    }
    return;
  }

  if (which == 0) {
    for (int idx = cid; idx < 64 * 32; idx += 256) {
      int r = idx >> 5, fc = (idx & 31) << 2;
      int n = n0 + r;
      float4 v = {0.f, 0.f, 0.f, 0.f};
      if (n < N_NODESC) v = *(const float4*)&nf[(size_t)n * 512 + fc];
      float vv[4] = {v.x, v.y, v.z, v.w};
      #pragma unroll
      for (int j = 0; j < 4; j++) sAh[r][fc + j] = f2bf_rne(vv[j]);
    }
    for (int g = 0; g < 3; g++) {
      if (g) __syncthreads();            // prev PASS's sB reads done
      const int tA = (g == 2) ? 10 : g * 2;
      STAGEB(tA)
      __syncthreads();
      f32x4 acc[8];
      #pragma unroll
      for (int nt = 0; nt < 8; nt++) acc[nt] = (f32x4){0.f, 0.f, 0.f, 0.f};
      GEMM_PASS1(acc)
      __syncthreads();
      STAGEB(tA + 1)
      __syncthreads();
      GEMM_PASS1(acc)
      float* op = (g == 0) ? P1s : ((g == 1) ? P1r : SU);
      #pragma unroll
      for (int q = 0; q < 4; q++) {
        int n = n0 + wid * 16 + lq * 4 + q;
        if (n < N_NODESC) {
          #pragma unroll
          for (int nt = 0; nt < 8; nt++)
            op[(size_t)n * 128 + nt * 16 + ln] = acc[nt][q] * INV128;
        }
      }
    }
  } else {
    int comp = which - 1;
    for (int idx = cid; idx < 64 * 128; idx += 256) {
      int r = idx >> 7, u = idx & 127;
      int n = n0 + r;
      float v = (n < N_NODESC) ? nf[(size_t)n * 512 + 128 + u * 3 + comp] : 0.f;
      sAh[r][u] = f2bf_rne(v);
    }
    STAGEB(12)
    __syncthreads();
    f32x4 acc[8];
    #pragma unroll
    for (int nt = 0; nt < 8; nt++) acc[nt] = (f32x4){0.f, 0.f, 0.f, 0.f};
    GEMM_PASS1(acc)
    __syncthreads();
    STAGEB(13)
    __syncthreads();
    GEMM_PASS1(acc)
    float* op = VU + (size_t)comp * NP;
    #pragma unroll
    for (int q = 0; q < 4; q++) {
      int n = n0 + wid * 16 + lq * 4 + q;
      if (n < N_NODESC) {
        #pragma unroll
        for (int nt = 0; nt < 8; nt++)
          op[(size_t)n * 128 + nt * 16 + ln] = acc[nt][q] * INV128;
      }
    }
  }
}

// ---------------- fused edge kernel (MFMA segmented reduce) ----------------
// Emit writes messages TRANSPOSED bf16 into sMsgT[col][edge] (pad 72 ushorts
// -> 144B rows, 16B-aligned b128 reads). Reduce: D[seg][col] =
// sum_e S[seg][e]*M[e][col] via mfma with ones-indicator A built in regs
// from sSegId. Per-plane y-scalars fold into emit at f32 precision.
// MFMA accumulation order is fixed -> deterministic.
#define MRED(P) {                                                              \
  __syncthreads();                     /* sMsgT complete */                    \
  const int nseg = sNseg;                                                      \
  f32x4 racc[4][2];                                                            \
  _Pragma("unroll") for (int mt = 0; mt < 4; mt++)                             \
    _Pragma("unroll") for (int t = 0; t < 2; t++)                              \
      racc[mt][t] = (f32x4){0.f, 0.f, 0.f, 0.f};                               \
  _Pragma("unroll") for (int mt = 0; mt < 4; mt++) {                           \
    if (mt * 16 < nseg) {                                                      \
      _Pragma("unroll") for (int s = 0; s < 2; s++) {                          \
        bf16x8 af;                                                             \
        _Pragma("unroll") for (int j = 0; j < 8; j++) {                        \
          int e = s * 32 + lq * 8 + j;                                         \
          af[j] = (sSegId[e] == mt * 16 + ln) ? (short)0x3F80 : (short)0;      \
        }                                                                      \
        _Pragma("unroll") for (int t = 0; t < 2; t++) {                        \
          bf16x8 bb = *(const bf16x8*)&sMsgT[(wid * 2 + t) * 16 + ln]          \
                                            [s * 32 + lq * 8];                 \
          racc[mt][t] = __builtin_amdgcn_mfma_f32_16x16x32_bf16(               \
              af, bb, racc[mt][t], 0, 0, 0);                                   \
        }                                                                      \
      }                                                                        \
    }                                                                          \
  }                                                                            \
  _Pragma("unroll") for (int mt = 0; mt < 4; mt++)                             \
    _Pragma("unroll") for (int t = 0; t < 2; t++)                              \
      _Pragma("unroll") for (int q = 0; q < 4; q++) {                          \
        int seg = mt * 16 + lq * 4 + q;                                        \
        if (seg < nseg) {                                                      \
          int col = (wid * 2 + t) * 16 + ln;                                   \
          float val = racc[mt][t][q];                                          \
          if (seg == 0 && contF)                                               \
            CONT[(size_t)gblk * 1024 + (P) * 128 + col] = val;                 \
          else                                                                 \
            MSG[(size_t)(P) * NP + (size_t)sSegNode[seg] * 128 + col] = val;   \
        }                                                                      \
      }                                                                        \
  __syncthreads();                     /* MFMA reads done before reuse */      \
}

__global__ __launch_bounds__(256, 3) void k_edge_fused(
    const float* __restrict__ P1s,
    const float* __restrict__ P1r,
    const float* __restrict__ SU,
    const float* __restrict__ VU,   // 3 planes
    const float* __restrict__ ef,
    const float* __restrict__ len,
    const float* __restrict__ ea,
    const int* __restrict__ eidx,
    const int* __restrict__ perm,
    const int* __restrict__ row_start,
    const float* __restrict__ W1,   // f32, tail rows 256..264
    const float* __restrict__ b1,
    const float* __restrict__ b2,
    const ushort* __restrict__ TT,
    float* __restrict__ MSG,        // 8 planes
    float* __restrict__ CONT)       // [NBLK_TOT][1024]
{
  __shared__ ushort sAh[64][132];   // h1/h2 (bf16 hi only)
  __shared__ ushort sB[128][132];   // full-K W tile; bf16 msg^T in emit
  __shared__ float sY4[64][4];
  __shared__ int sSnd[64], sRcv[64], sEid[64], sSegId[64];
  __shared__ int sSegStart[65], sSegNode[64];
  __shared__ int sNseg, sContFirst;
  ushort (*sMsgT)[72] = (ushort (*)[72])&sB[0][0];  // 128*72*2=18432 <= 33792

  // bijective XCD swizzle (m204): nwg=2500, q=312, r=4
  const int bid = blockIdx.x;
  const int xcd = bid & 7, sub = bid >> 3;
  const int gblk = (xcd < 4) ? (xcd * 313 + sub)
                             : (1252 + (xcd - 4) * 312 + sub);
  const int j0 = gblk * 64;
  const int cid = threadIdx.x;
  const int wid = cid >> 6;
  const int lane = cid & 63;
  const int lq = lane >> 4;
  const int ln = lane & 15;
  const int ar = wid * 16 + ln;
  const uint4* ttp = (const uint4*)TT;

  // meta + segment list + per-edge segment id (wave 0)
  if (cid < 64) {
    int r = cid;
    int e = perm[j0 + r];
    int snd = eidx[e];
    int rcv = eidx[N_EDGESC + e];
    sSnd[r] = snd;
    sRcv[r] = rcv;
    sEid[r] = e;
    *(float4*)&sY4[r][0] = *(const float4*)&ea[(size_t)e * 4];
    int prev = __shfl_up(rcv, 1);
    bool flag = (r == 0) || (rcv != prev);
    unsigned long long mask = __ballot(flag ? 1 : 0);
    // inclusive-prefix popcount WITHOUT 1<<64 UB (r=63: full mask)
    sSegId[r] = __popcll(mask & (~0ull >> (63 - r))) - 1;
    if (flag) {
      int rank = __popcll(mask & ((1ull << r) - 1ull));
      sSegStart[rank] = r;
      sSegNode[rank] = rcv;
    }
    if (r == 0) {
      sNseg = __popcll(mask);
      sContFirst = (row_start[rcv] != j0) ? 1 : 0;
    }
    if (r == 63) sSegStart[__popcll(mask)] = 64;
  }
  __syncthreads();                       // B1
  const bool contF = (sContFirst != 0);

  // ---------- h1 = silu(P1s[snd] + P1r[rcv] + tail + b1)  [no GEMM] --------
  for (int idx = cid; idx < 64 * 32; idx += 256) {
    int r = idx >> 5, c4 = (idx & 31) << 2;
    int ns = sSnd[r], nr = sRcv[r];
    float4 a = *(const float4*)&P1s[(size_t)ns * 128 + c4];
    float4 b = *(const float4*)&P1r[(size_t)nr * 128 + c4];
    int e = sEid[r];
    float el[9];
    float4 e0 = *(const float4*)&ef[(size_t)e * 8];
    float4 e1 = *(const float4*)&ef[(size_t)e * 8 + 4];
    el[0] = e0.x; el[1] = e0.y; el[2] = e0.z; el[3] = e0.w;
    el[4] = e1.x; el[5] = e1.y; el[6] = e1.z; el[7] = e1.w;
    el[8] = len[e];
    float4 bb = *(const float4*)&b1[c4];
    float v[4] = {a.x + b.x + bb.x, a.y + b.y + bb.y,
                  a.z + b.z + bb.z, a.w + b.w + bb.w};
    #pragma unroll
    for (int t = 0; t < 9; t++) {
      float4 wt = *(const float4*)&W1[(size_t)(256 + t) * 128 + c4];
      float elt = el[t];
      v[0] += elt * wt.x; v[1] += elt * wt.y;
      v[2] += elt * wt.z; v[3] += elt * wt.w;
    }
    #pragma unroll
    for (int j = 0; j < 4; j++)
      sAh[r][c4 + j] = f2bf_rne(silu_f(v[j]));
  }
  STAGEB(4)                              // W2.hi, overlapped with h1 compute
  __syncthreads();                       // B2

  // ---------- layer 2 (A = h1-hi 1-term, B = W2 hi+lo) ----------
  f32x4 acc2[8];
  #pragma unroll
  for (int nt = 0; nt < 8; nt++) acc2[nt] = (f32x4){0.f, 0.f, 0.f, 0.f};
  GEMM_PASS1(acc2)
  __syncthreads();                       // B3
  STAGEB(5)                              // W2.lo
  __syncthreads();                       // B4
  GEMM_PASS1(acc2)
  __syncthreads();                       // B5 (sB reads done before restage)
  #pragma unroll
  for (int nt = 0; nt < 8; nt++) {
    int col = nt * 16 + ln;
    float bb2 = b2[col];
    #pragma unroll
    for (int q = 0; q < 4; q++) {
      int rr = wid * 16 + lq * 4 + q;
      sAh[rr][col] = f2bf_rne(silu_f(acc2[nt][q] + bb2));
    }
  }

  // layer-3 preamble
  int erow[4], esnd[4];
  float y0r[4], y1r3[4][3];
  #pragma unroll
  for (int q = 0; q < 4; q++) {
    int rr = wid * 16 + lq * 4 + q;
    erow[q] = rr;
    esnd[q] = sSnd[rr];
    y0r[q] = sY4[rr][0];
    #pragma unroll
    for (int i = 0; i < 3; i++) y1r3[q][i] = sY4[rr][1 + i];
  }
  float se[4][8];
  #pragma unroll
  for (int q = 0; q < 4; q++)
    #pragma unroll
    for (int nt = 0; nt < 8; nt++)
      se[q][nt] = SU[(size_t)esnd[q] * 128 + nt * 16 + ln];
  float dacc[4][8];

  STAGEB(6)
  __syncthreads();                       // B6

  // ----- cb0 (tile t6): plane 0 = sum(acc*se*y0) -----
  {
    f32x4 acc3[8];
    #pragma unroll
    for (int nt = 0; nt < 8; nt++) acc3[nt] = (f32x4){0.f, 0.f, 0.f, 0.f};
    GEMM_PASS1(acc3)
    __syncthreads();                     // sB free -> sMsgT
    #pragma unroll
    for (int q = 0; q < 4; q++)
      #pragma unroll
      for (int nt = 0; nt < 8; nt++)
        sMsgT[nt * 16 + ln][erow[q]] =
            f2bf_rne(acc3[nt][q] * se[q][nt] * y0r[q]);
    MRED(0)
    STAGEB(7)
    __syncthreads();
  }
  // ----- cb1 (tile t7): planes 2,3,4 = sum(acc*se*y1[i]) -----
  {
    f32x4 acc3[8];
    #pragma unroll
    for (int nt = 0; nt < 8; nt++) acc3[nt] = (f32x4){0.f, 0.f, 0.f, 0.f};
    GEMM_PASS1(acc3)
    __syncthreads();
    #pragma unroll
    for (int i = 0; i < 3; i++) {
      #pragma unroll
      for (int q = 0; q < 4; q++)
        #pragma unroll
        for (int nt = 0; nt < 8; nt++)
          sMsgT[nt * 16 + ln][erow[q]] =
              f2bf_rne(acc3[nt][q] * se[q][nt] * y1r3[q][i]);
      MRED(2 + i)
    }
    STAGEB(8)
    __syncthreads();
  }
  // ----- cb2 (tile t8): planes 5,6,7 = sum(acc*vu_pi*y0) -----
  {
    f32x4 acc3[8];
    #pragma unroll
    for (int nt = 0; nt < 8; nt++) acc3[nt] = (f32x4){0.f, 0.f, 0.f, 0.f};
    GEMM_PASS1(acc3)
    __syncthreads();
    #pragma unroll
    for (int pi = 0; pi < 3; pi++) {
      float vu[4][8];
      #pragma unroll
      for (int q = 0; q < 4; q++)
        #pragma unroll
        for (int nt = 0; nt < 8; nt++) {
          vu[q][nt] = VU[(size_t)pi * NP + (size_t)esnd[q] * 128 + nt * 16 + ln];
          if (pi == 0) dacc[q][nt] = vu[q][nt] * y1r3[q][0];
          else dacc[q][nt] += vu[q][nt] * y1r3[q][pi];
        }
      #pragma unroll
      for (int q = 0; q < 4; q++)
        #pragma unroll
        for (int nt = 0; nt < 8; nt++)
          sMsgT[nt * 16 + ln][erow[q]] =
              f2bf_rne(acc3[nt][q] * vu[q][nt] * y0r[q]);
      MRED(5 + pi)
    }
    STAGEB(9)
    __syncthreads();
  }
  // ----- cb3 (tile t9): plane 1 = sum(acc*dacc)/sqrt(3) -----
  {
    f32x4 acc3[8];
    #pragma unroll
    for (int nt = 0; nt < 8; nt++) acc3[nt] = (f32x4){0.f, 0.f, 0.f, 0.f};
    GEMM_PASS1(acc3)
    __syncthreads();
    #pragma unroll
    for (int q = 0; q < 4; q++)
      #pragma unroll
      for (int nt = 0; nt < 8; nt++)
        sMsgT[nt * 16 + ln][erow[q]] =
            f2bf_rne(acc3[nt][q] * dacc[q][nt] * INV_SQRT3C);
    MRED(1)
  }
}

// ---------------- fixup: CONT partials + deg-0 zero-fill (no MSG memset) ---
__global__ __launch_bounds__(256) void k_fixup(float* __restrict__ MSG,
                                               const float* __restrict__ CONT,
                                               const int* __restrict__ row_start) {
  int t = blockIdx.x * 256 + threadIdx.x;
  int n = t >> 5;
  int c4 = (t & 31) * 4;
  if (n >= N_NODESC) return;
  int s = row_start[n], e = row_start[n + 1];
  if (e <= s) {
    float4 z = {0.f, 0.f, 0.f, 0.f};
    #pragma unroll
    for (int p = 0; p < 8; p++)
      *(float4*)&MSG[(size_t)p * NP + (size_t)n * 128 + c4] = z;
    return;
  }
  int b0 = s >> 6, b1 = (e - 1) >> 6;
  if (b1 <= b0) return;
  for (int p = 0; p < 8; p++) {
    float4 v = *(float4*)&MSG[(size_t)p * NP + (size_t)n * 128 + c4];
    for (int b = b0 + 1; b <= b1; b++) {
      const float4 u = *(const float4*)&CONT[(size_t)b * 1024 + p * 128 + c4];
      v.x += u.x; v.y += u.y; v.z += u.z; v.w += u.w;
    }
    *(float4*)&MSG[(size_t)p * NP + (size_t)n * 128 + c4] = v;
  }
}

// ---------------- K4: output GEMMs (MFMA, A 1-term, 3 blk/CU) --------------
__global__ __launch_bounds__(256, 3) void k_out(
    const float* __restrict__ MSG,
    const ushort* __restrict__ TT,
    float* __restrict__ out)
{
  __shared__ ushort sAh[64][132];
  __shared__ ushort sB[128][132];
  const int n0 = blockIdx.x * 64;
  const int y = blockIdx.y;
  const int cid = threadIdx.x;
  const int wid = cid >> 6;
  const int lane = cid & 63;
  const int lq = lane >> 4;
  const int ln = lane & 15;
  const int ar = wid * 16 + ln;
  const uint4* ttp = (const uint4*)TT;
  const int pA = (y == 0) ? 0 : (1 + y);
  const int pB = (y == 0) ? 1 : (4 + y);
  const int tbase = 16 + ((y == 0) ? 0 : 4);

  f32x4 acc[8];
  #pragma unroll
  for (int nt = 0; nt < 8; nt++) acc[nt] = (f32x4){0.f, 0.f, 0.f, 0.f};

  for (int kh = 0; kh < 2; kh++) {
    if (kh) __syncthreads();             // protect previous PASS reads of sAh
    const int p = kh ? pB : pA;
    for (int idx = cid; idx < 64 * 32; idx += 256) {
      int r = idx >> 5, fc = (idx & 31) << 2;
      int n = n0 + r;
      float4 v = {0.f, 0.f, 0.f, 0.f};
      if (n < N_NODESC) v = *(const float4*)&MSG[(size_t)p * NP + (size_t)n * 128 + fc];
      float vv[4] = {v.x, v.y, v.z, v.w};
      #pragma unroll
      for (int j = 0; j < 4; j++) sAh[r][fc + j] = f2bf_rne(vv[j]);
    }
    STAGEB(tbase + kh * 2)
    __syncthreads();
    GEMM_PASS1(acc)
    __syncthreads();
    STAGEB(tbase + kh * 2 + 1)
    __syncthreads();
    GEMM_PASS1(acc)
  }
  #pragma unroll
  for (int q = 0; q < 4; q++) {
    int n = n0 + wid * 16 + lq * 4 + q;
    if (n < N_NODESC) {
      #pragma unroll
      for (int nt = 0; nt < 8; nt++)
        out[(size_t)n * 512 + (size_t)(nt * 16 + ln) * 4 + y] = acc[nt][q] * SCALE_OUT;
    }
  }
}

extern "C" void kernel_launch(void* const* d_in, const int* in_sizes, int n_in,
                              void* d_out, int out_size, void* d_ws, size_t ws_size,
                              hipStream_t stream) {
  const float* nf  = (const float*)d_in[0];
  const float* ea  = (const float*)d_in[1];
  const float* ef  = (const float*)d_in[2];
  const float* len = (const float*)d_in[3];
  const int*   ei  = (const int*)d_in[4];
  const float* Wsc = (const float*)d_in[5];
  const float* Wu0 = (const float*)d_in[6];
  const float* Wu1 = (const float*)d_in[7];
  const float* W1  = (const float*)d_in[8];
  const float* b1  = (const float*)d_in[9];
  const float* W2  = (const float*)d_in[10];
  const float* b2  = (const float*)d_in[11];
  const float* W3  = (const float*)d_in[12];
  const float* Wo0 = (const float*)d_in[13];
  const float* Wo1 = (const float*)d_in[14];
  float* out = (float*)d_out;
  float* ws  = (float*)d_ws;

  const size_t NPs = (size_t)NP;
  float* P1s  = ws;                            // 1 plane
  float* P1r  = ws + NPs;                      // 1 plane
  float* SU   = ws + 2 * NPs;                  // 1 plane
  float* VU   = ws + 3 * NPs;                  // 3 planes
  float* MSG  = ws + 6 * NPs;                  // 8 planes
  float* CONT = ws + 14 * NPs;                 // NBLK_TOT*1024
  ushort* TT  = (ushort*)(CONT + (size_t)NBLK_TOT * 1024);  // 24*16384 ushorts
  int* perm      = (int*)(TT + 24 * 16384);
  int* deg       = perm + N_EDGESC;
  int* cursor    = deg + N_NODESC;
  int* row_start = cursor + N_NODESC;          // N_NODESC+1 ints

  hipMemsetAsync(deg, 0, N_NODESC * sizeof(int), stream);

  k_histprep<<<1329, 256, 0, stream>>>(ei, deg, W2, W3, Wu0, Wu1, Wo0, Wo1, TT);
  k_scan<<<1, 1024, 0, stream>>>(deg, row_start, cursor);
  k_scatter<<<(N_EDGESC + 255) / 256, 256, 0, stream>>>(ei, row_start, cursor, perm);
  k_wcomp<<<dim3(2, 2), 256, 0, stream>>>(Wsc, W1, TT);

  // y=0..3: node up-projections; y=4: fused per-node perm sort
  k_node_up<<<dim3(157, 5), 256, 0, stream>>>(nf, TT, P1s, P1r, SU, VU,
                                              perm, row_start);

  k_edge_fused<<<NBLK_TOT, 256, 0, stream>>>(P1s, P1r, SU, VU, ef, len, ea, ei,
                                             perm, row_start, W1, b1, b2, TT,
                                             MSG, CONT);

  k_fixup<<<(N_NODESC * 32 + 255) / 256, 256, 0, stream>>>(MSG, CONT, row_start);
  k_out<<<dim3(157, 4), 256, 0, stream>>>(MSG, TT, out);
}

// Round 17
// 284.602 us; speedup vs baseline: 1.2502x; 1.2502x over previous
//
#include <hip/hip_runtime.h>

#define N_NODESC 10000
#define N_EDGESC 160000
#define NBLK_TOT 2500                 // N_EDGESC/64
#define NP       (N_NODESC*128)       // plane size (floats)
#define INV128   0.08838834764831845f // 1/sqrt(128)
#define INV_SQRT3C 0.5773502691896258f
#define SCALE_OUT 0.00390625f         // (1/sqrt(256))/16

typedef __attribute__((ext_vector_type(8))) short bf16x8;
typedef __attribute__((ext_vector_type(4))) float f32x4;

__device__ __forceinline__ float silu_f(float x) {
  return x / (1.f + __expf(-x));
}
__device__ __forceinline__ ushort f2bf_rne(float x) {
  uint u = __float_as_uint(x);
  uint r = (u + 0x7FFFu + ((u >> 16) & 1u)) >> 16;
  return (ushort)r;
}
__device__ __forceinline__ float bf2f(ushort h) {
  return __uint_as_float(((uint)h) << 16);
}

// ---------------- merged: edge histogram + weight prep ---------------------
__global__ __launch_bounds__(256) void k_histprep(
    const int* __restrict__ eidx, int* __restrict__ deg,
    const float* __restrict__ W2, const float* __restrict__ W3,
    const float* __restrict__ Wu0, const float* __restrict__ Wu1,
    const float* __restrict__ Wo0, const float* __restrict__ Wo1,
    ushort* __restrict__ TT) {
  const int bid = blockIdx.x;
  if (bid < 625) {
    int e = bid * 256 + threadIdx.x;
    if (e < N_EDGESC) atomicAdd(&deg[eidx[N_EDGESC + e]], 1);
    return;
  }
  int id = (bid - 625) * 256 + threadIdx.x;
  if (id < 16384) {                   // W2
    int k = id >> 7, n = id & 127;
    float v = W2[k * 128 + n];
    ushort hi = f2bf_rne(v);
    TT[4 * 16384 + n * 128 + k] = hi;
    TT[5 * 16384 + n * 128 + k] = f2bf_rne(v - bf2f(hi));
  } else if (id < 81920) {            // W3 hi only
    int s = id - 16384;
    int k = s >> 9, col = s & 511;
    int cb = col >> 7, n = col & 127;
    TT[(6 + cb) * 16384 + n * 128 + k] = f2bf_rne(W3[k * 512 + col]);
  } else if (id < 114688) {           // Wu0 (t10/11), Wu1 (t12/13)
    int t = id - 81920;
    int w = t >> 14, r = t & 16383;
    int k = r >> 7, n = r & 127;
    const float* W = w ? Wu1 : Wu0;
    float v = W[k * 128 + n];
    ushort hi = f2bf_rne(v);
    TT[(10 + w * 2) * 16384 + n * 128 + k] = hi;
    TT[(11 + w * 2) * 16384 + n * 128 + k] = f2bf_rne(v - bf2f(hi));
  } else if (id < 180224) {           // Wo0/Wo1 -> t16..23
    int t = id - 114688;
    int w = t >> 15, r = t & 32767;
    int k = r >> 7, n = r & 127;
    const float* W = w ? Wo1 : Wo0;
    float v = W[k * 128 + n];
    int kh = k >> 7, kk = k & 127;
    ushort hi = f2bf_rne(v);
    TT[(16 + w * 4 + kh * 2) * 16384 + n * 128 + kk] = hi;
    TT[(17 + w * 4 + kh * 2) * 16384 + n * 128 + kk] = f2bf_rne(v - bf2f(hi));
  }
}

__global__ __launch_bounds__(1024) void k_scan(const int* __restrict__ deg,
                                               int* __restrict__ row_start,
                                               int* __restrict__ cursor) {
  __shared__ int buf[1024];
  const int t = threadIdx.x;
  for (int i = t; i < N_NODESC; i += 1024) cursor[i] = 0;
  int d[10];
  int loc = 0;
  #pragma unroll
  for (int i = 0; i < 10; i++) {
    int n = t * 10 + i;
    d[i] = (n < N_NODESC) ? deg[n] : 0;
    loc += d[i];
  }
  buf[t] = loc;
  __syncthreads();
  int v = loc;
  for (int off = 1; off < 1024; off <<= 1) {
    int u = (t >= off) ? buf[t - off] : 0;
    __syncthreads();
    v += u;
    buf[t] = v;
    __syncthreads();
  }
  int run = v - loc;
  #pragma unroll
  for (int i = 0; i < 10; i++) {
    int n = t * 10 + i;
    if (n < N_NODESC) row_start[n] = run;
    run += d[i];
  }
  if (t == 1023) row_start[N_NODESC] = v;
}

__global__ __launch_bounds__(256) void k_scatter(const int* __restrict__ eidx,
                                                 const int* __restrict__ row_start,
                                                 int* __restrict__ cursor,
                                                 int* __restrict__ perm) {
  int e = blockIdx.x * 256 + threadIdx.x;
  if (e < N_EDGESC) {
    int r = eidx[N_EDGESC + e];
    int pos = row_start[r] + atomicAdd(&cursor[r], 1);
    perm[pos] = e;
  }
}

// ---------------- weight compose: TT[t0..3] = bf16(Wsc @ W1block) ----------
__global__ __launch_bounds__(256) void k_wcomp(
    const float* __restrict__ Wsc, const float* __restrict__ W1,
    ushort* __restrict__ TT) {
  __shared__ float sA2[64][132];
  __shared__ float sW2[128][128];
  const int rh = blockIdx.x;   // output row half (0/1)
  const int wb = blockIdx.y;   // which W1 block (0: rows 0-127, 1: 128-255)
  for (int idx = threadIdx.x; idx < 128 * 32; idx += 256) {
    int k = idx >> 5, fc = (idx & 31) << 2;
    *(float4*)&sW2[k][fc] = *(const float4*)&W1[(wb * 128 + k) * 128 + fc];
  }
  for (int idx = threadIdx.x; idx < 64 * 32; idx += 256) {
    int i = idx >> 5, fc = (idx & 31) << 2;
    *(float4*)&sA2[i][fc] = *(const float4*)&Wsc[(rh * 64 + i) * 128 + fc];
  }
  __syncthreads();
  const int r0 = (threadIdx.x >> 4) * 4;
  const int c0 = (threadIdx.x & 15) * 8;
  float acc[4][8] = {};
  #pragma unroll 4
  for (int k = 0; k < 128; k++) {
    float a[4];
    #pragma unroll
    for (int j = 0; j < 4; j++) a[j] = sA2[r0 + j][k];
    float w[8];
    *(float4*)&w[0] = *(const float4*)&sW2[k][c0];
    *(float4*)&w[4] = *(const float4*)&sW2[k][c0 + 4];
    #pragma unroll
    for (int j = 0; j < 4; j++)
      #pragma unroll
      for (int c = 0; c < 8; c++) acc[j][c] += a[j] * w[c];
  }
  #pragma unroll
  for (int j = 0; j < 4; j++) {
    int u = rh * 64 + r0 + j;    // input-feature index (k of B-tile)
    #pragma unroll
    for (int c = 0; c < 8; c++) {
      float v = acc[j][c];
      ushort hi = f2bf_rne(v);
      TT[(wb * 2 + 0) * 16384 + (c0 + c) * 128 + u] = hi;
      TT[(wb * 2 + 1) * 16384 + (c0 + c) * 128 + u] = f2bf_rne(v - bf2f(hi));
    }
  }
}

// ---------------- shared GEMM macro (A 1-term, full-K tile) ----------------
#define GEMM_PASS1(ACC)                                                        \
  _Pragma("unroll") for (int s = 0; s < 4; s++) {                              \
    bf16x8 ah = *(const bf16x8*)&sAh[ar][s * 32 + lq * 8];                     \
    _Pragma("unroll") for (int nt = 0; nt < 8; nt++) {                         \
      bf16x8 bb = *(const bf16x8*)&sB[nt * 16 + ln][s * 32 + lq * 8];          \
      ACC[nt] = __builtin_amdgcn_mfma_f32_16x16x32_bf16(ah, bb, ACC[nt], 0, 0, 0); \
    }                                                                          \
  }

// transient staging: load whole tile to short-lived regs, write to LDS
#define STAGEB(T) { uint4 tv[8];                                               \
  _Pragma("unroll") for (int i = 0; i < 8; i++)                                \
    tv[i] = ttp[(T) * 2048 + cid + 256 * i];                                   \
  _Pragma("unroll") for (int i = 0; i < 8; i++) {                              \
    int c = cid + 256 * i;                                                     \
    *(uint4*)&sB[c >> 4][(c & 15) * 8] = tv[i]; } }

// ---------------- K1: node up-projections (MFMA, A 1-term, 3 blk/CU) -------
// which 0: P1s+P1r+SU (shared A = s_in); which 1..3: VU comp (which-1);
// which 4: per-node insertion sort of perm segments (fused k_sortseg)
__global__ __launch_bounds__(256, 3) void k_node_up(
    const float* __restrict__ nf,
    const ushort* __restrict__ TT,
    float* __restrict__ P1s,
    float* __restrict__ P1r,
    float* __restrict__ SU,
    float* __restrict__ VU,
    int* __restrict__ perm,
    const int* __restrict__ row_start)
{
  __shared__ ushort sAh[64][132];
  __shared__ ushort sB[128][132];
  const int n0 = blockIdx.x * 64;
  const int which = blockIdx.y;
  const int cid = threadIdx.x;
  const int wid = cid >> 6;
  const int lane = cid & 63;
  const int lq = lane >> 4;
  const int ln = lane & 15;
  const int ar = wid * 16 + ln;
  const uint4* ttp = (const uint4*)TT;

  if (which == 4) {
    // fused sortseg: deterministic ascending edge-id order per node
    int n = blockIdx.x * 256 + cid;
    if (n < N_NODESC) {
      int s = row_start[n], e = row_start[n + 1];
      for (int i = s + 1; i < e; i++) {
        int key = perm[i];
        int j = i - 1;
        while (j >= s && perm[j] > key) { perm[j + 1] = perm[j]; j--; }
        perm[j + 1] = key;
      }
    }
    return;
  }

  if (which == 0) {
    for (int idx = cid; idx < 64 * 32; idx += 256) {
      int r = idx >> 5, fc = (idx & 31) << 2;
      int n = n0 + r;
      float4 v = {0.f, 0.f, 0.f, 0.f};
      if (n < N_NODESC) v = *(const float4*)&nf[(size_t)n * 512 + fc];
      float vv[4] = {v.x, v.y, v.z, v.w};
      #pragma unroll
      for (int j = 0; j < 4; j++) sAh[r][fc + j] = f2bf_rne(vv[j]);
    }
    for (int g = 0; g < 3; g++) {
      if (g) __syncthreads();            // prev PASS's sB reads done
      const int tA = (g == 2) ? 10 : g * 2;
      STAGEB(tA)
      __syncthreads();
      f32x4 acc[8];
      #pragma unroll
      for (int nt = 0; nt < 8; nt++) acc[nt] = (f32x4){0.f, 0.f, 0.f, 0.f};
      GEMM_PASS1(acc)
      __syncthreads();
      STAGEB(tA + 1)
      __syncthreads();
      GEMM_PASS1(acc)
      float* op = (g == 0) ? P1s : ((g == 1) ? P1r : SU);
      #pragma unroll
      for (int q = 0; q < 4; q++) {
        int n = n0 + wid * 16 + lq * 4 + q;
        if (n < N_NODESC) {
          #pragma unroll
          for (int nt = 0; nt < 8; nt++)
            op[(size_t)n * 128 + nt * 16 + ln] = acc[nt][q] * INV128;
        }
      }
    }
  } else {
    int comp = which - 1;
    for (int idx = cid; idx < 64 * 128; idx += 256) {
      int r = idx >> 7, u = idx & 127;
      int n = n0 + r;
      float v = (n < N_NODESC) ? nf[(size_t)n * 512 + 128 + u * 3 + comp] : 0.f;
      sAh[r][u] = f2bf_rne(v);
    }
    STAGEB(12)
    __syncthreads();
    f32x4 acc[8];
    #pragma unroll
    for (int nt = 0; nt < 8; nt++) acc[nt] = (f32x4){0.f, 0.f, 0.f, 0.f};
    GEMM_PASS1(acc)
    __syncthreads();
    STAGEB(13)
    __syncthreads();
    GEMM_PASS1(acc)
    float* op = VU + (size_t)comp * NP;
    #pragma unroll
    for (int q = 0; q < 4; q++) {
      int n = n0 + wid * 16 + lq * 4 + q;
      if (n < N_NODESC) {
        #pragma unroll
        for (int nt = 0; nt < 8; nt++)
          op[(size_t)n * 128 + nt * 16 + ln] = acc[nt][q] * INV128;
      }
    }
  }
}

// ---------------- fused edge kernel (L1 factorized; A-1-term; 3 blk/CU) ----
// parallel segmented reduce (f32 messages, 8-batched, deterministic order)
#define REDUCE(P, MI) {                                                        \
  const int ntask = sNseg << 7;                                                \
  for (int task = cid; task < ntask; task += 256) {                            \
    const int si = task >> 7, col = task & 127;                                \
    const int s = sSegStart[si], e = sSegStart[si + 1];                        \
    float sum = 0.f;                                                           \
    int e2 = s;                                                                \
    for (; e2 + 8 <= e; e2 += 8) {                                             \
      float m0 = sMsg[e2][col],     m1 = sMsg[e2 + 1][col];                    \
      float m2 = sMsg[e2 + 2][col], m3 = sMsg[e2 + 3][col];                    \
      float m4 = sMsg[e2 + 4][col], m5 = sMsg[e2 + 5][col];                    \
      float m6 = sMsg[e2 + 6][col], m7 = sMsg[e2 + 7][col];                    \
      if ((MI) >= 0) {                                                         \
        const int mi = (MI) >= 0 ? (MI) : 0;                                   \
        sum += m0 * sY4[e2][mi];     sum += m1 * sY4[e2 + 1][mi];              \
        sum += m2 * sY4[e2 + 2][mi]; sum += m3 * sY4[e2 + 3][mi];              \
        sum += m4 * sY4[e2 + 4][mi]; sum += m5 * sY4[e2 + 5][mi];              \
        sum += m6 * sY4[e2 + 6][mi]; sum += m7 * sY4[e2 + 7][mi];              \
      } else { sum += m0; sum += m1; sum += m2; sum += m3;                     \
               sum += m4; sum += m5; sum += m6; sum += m7; }                   \
    }                                                                          \
    for (; e2 < e; e2++) {                                                     \
      float mv = sMsg[e2][col];                                                \
      sum += ((MI) >= 0) ? mv * sY4[e2][(MI) >= 0 ? (MI) : 0] : mv;            \
    }                                                                          \
    if (si == 0 && contF)                                                      \
      CONT[(size_t)gblk * 1024 + (P) * 128 + col] = sum;                       \
    else                                                                       \
      MSG[(size_t)(P) * NP + (size_t)sSegNode[si] * 128 + col] = sum;          \
  } }

// one-pass reduce for planes 2,3,4 (y1a/y1b/y1c × shared sMsg)
#define REDUCE3 {                                                              \
  const int ntask = sNseg << 7;                                                \
  for (int task = cid; task < ntask; task += 256) {                            \
    const int si = task >> 7, col = task & 127;                                \
    const int s = sSegStart[si], e = sSegStart[si + 1];                        \
    float s0 = 0.f, s1 = 0.f, s2 = 0.f;                                        \
    int e2 = s;                                                                \
    for (; e2 + 4 <= e; e2 += 4) {                                             \
      _Pragma("unroll") for (int u = 0; u < 4; u++) {                          \
        float mv = sMsg[e2 + u][col];                                          \
        s0 += mv * sY4[e2 + u][1];                                             \
        s1 += mv * sY4[e2 + u][2];                                             \
        s2 += mv * sY4[e2 + u][3];                                             \
      }                                                                        \
    }                                                                          \
    for (; e2 < e; e2++) {                                                     \
      float mv = sMsg[e2][col];                                                \
      s0 += mv * sY4[e2][1]; s1 += mv * sY4[e2][2]; s2 += mv * sY4[e2][3];     \
    }                                                                          \
    if (si == 0 && contF) {                                                    \
      CONT[(size_t)gblk * 1024 + 2 * 128 + col] = s0;                          \
      CONT[(size_t)gblk * 1024 + 3 * 128 + col] = s1;                          \
      CONT[(size_t)gblk * 1024 + 4 * 128 + col] = s2;                          \
    } else {                                                                   \
      size_t nb = (size_t)sSegNode[si] * 128 + col;                            \
      MSG[2 * (size_t)NP + nb] = s0;                                           \
      MSG[3 * (size_t)NP + nb] = s1;                                           \
      MSG[4 * (size_t)NP + nb] = s2;                                           \
    }                                                                          \
  } }

__global__ __launch_bounds__(256, 3) void k_edge_fused(
    const float* __restrict__ P1s,
    const float* __restrict__ P1r,
    const float* __restrict__ SU,
    const float* __restrict__ VU,   // 3 planes
    const float* __restrict__ ef,
    const float* __restrict__ len,
    const float* __restrict__ ea,
    const int* __restrict__ eidx,
    const int* __restrict__ perm,
    const int* __restrict__ row_start,
    const float* __restrict__ W1,   // f32, tail rows 256..264
    const float* __restrict__ b1,
    const float* __restrict__ b2,
    const ushort* __restrict__ TT,
    float* __restrict__ MSG,        // 8 planes
    float* __restrict__ CONT)       // [NBLK_TOT][1024]
{
  __shared__ ushort sAh[64][132];   // h1/h2 (bf16 hi only)
  __shared__ ushort sB[128][132];   // full-K W tile; f32 msg buffer in emit
  __shared__ float sY4[64][4];
  __shared__ int sSnd[64], sRcv[64], sEid[64];
  __shared__ int sSegStart[65], sSegNode[64];
  __shared__ int sNseg, sContFirst;
  float (*sMsg)[132] = (float (*)[132])&sB[0][0];  // 64*132*4 = 33792 = sizeof(sB)

  // bijective XCD swizzle (m204): nwg=2500, q=312, r=4
  const int bid = blockIdx.x;
  const int xcd = bid & 7, sub = bid >> 3;
  const int gblk = (xcd < 4) ? (xcd * 313 + sub)
                             : (1252 + (xcd - 4) * 312 + sub);
  const int j0 = gblk * 64;
  const int cid = threadIdx.x;
  const int wid = cid >> 6;
  const int lane = cid & 63;
  const int lq = lane >> 4;
  const int ln = lane & 15;
  const int ar = wid * 16 + ln;
  const uint4* ttp = (const uint4*)TT;

  // meta + segment list (wave 0)
  if (cid < 64) {
    int r = cid;
    int e = perm[j0 + r];
    int snd = eidx[e];
    int rcv = eidx[N_EDGESC + e];
    sSnd[r] = snd;
    sRcv[r] = rcv;
    sEid[r] = e;
    *(float4*)&sY4[r][0] = *(const float4*)&ea[(size_t)e * 4];
    int prev = __shfl_up(rcv, 1);
    bool flag = (r == 0) || (rcv != prev);
    unsigned long long mask = __ballot(flag ? 1 : 0);
    if (flag) {
      int rank = __popcll(mask & ((1ull << r) - 1ull));
      sSegStart[rank] = r;
      sSegNode[rank] = rcv;
    }
    if (r == 0) {
      sNseg = __popcll(mask);
      sContFirst = (row_start[rcv] != j0) ? 1 : 0;
    }
    if (r == 63) sSegStart[__popcll(mask)] = 64;
  }
  __syncthreads();                       // B1
  const bool contF = (sContFirst != 0);

  // ---------- h1 = silu(P1s[snd] + P1r[rcv] + tail + b1)  [no GEMM] --------
  for (int idx = cid; idx < 64 * 32; idx += 256) {
    int r = idx >> 5, c4 = (idx & 31) << 2;
    int ns = sSnd[r], nr = sRcv[r];
    float4 a = *(const float4*)&P1s[(size_t)ns * 128 + c4];
    float4 b = *(const float4*)&P1r[(size_t)nr * 128 + c4];
    int e = sEid[r];
    float el[9];
    float4 e0 = *(const float4*)&ef[(size_t)e * 8];
    float4 e1 = *(const float4*)&ef[(size_t)e * 8 + 4];
    el[0] = e0.x; el[1] = e0.y; el[2] = e0.z; el[3] = e0.w;
    el[4] = e1.x; el[5] = e1.y; el[6] = e1.z; el[7] = e1.w;
    el[8] = len[e];
    float4 bb = *(const float4*)&b1[c4];
    float v[4] = {a.x + b.x + bb.x, a.y + b.y + bb.y,
                  a.z + b.z + bb.z, a.w + b.w + bb.w};
    #pragma unroll
    for (int t = 0; t < 9; t++) {
      float4 wt = *(const float4*)&W1[(size_t)(256 + t) * 128 + c4];
      float elt = el[t];
      v[0] += elt * wt.x; v[1] += elt * wt.y;
      v[2] += elt * wt.z; v[3] += elt * wt.w;
    }
    #pragma unroll
    for (int j = 0; j < 4; j++)
      sAh[r][c4 + j] = f2bf_rne(silu_f(v[j]));
  }
  STAGEB(4)                              // W2.hi, overlapped with h1 compute
  __syncthreads();                       // B2

  // ---------- layer 2 (A = h1-hi 1-term, B = W2 hi+lo) ----------
  f32x4 acc2[8];
  #pragma unroll
  for (int nt = 0; nt < 8; nt++) acc2[nt] = (f32x4){0.f, 0.f, 0.f, 0.f};
  GEMM_PASS1(acc2)
  __syncthreads();                       // B3
  STAGEB(5)                              // W2.lo
  __syncthreads();                       // B4
  GEMM_PASS1(acc2)
  __syncthreads();                       // B5 (sB reads done before restage)
  #pragma unroll
  for (int nt = 0; nt < 8; nt++) {
    int col = nt * 16 + ln;
    float bb2 = b2[col];
    #pragma unroll
    for (int q = 0; q < 4; q++) {
      int rr = wid * 16 + lq * 4 + q;
      sAh[rr][col] = f2bf_rne(silu_f(acc2[nt][q] + bb2));
    }
  }

  // layer-3 preamble: per-edge scalars + se gather (hides under stage+GEMM)
  int erow[4], esnd[4];
  float y0r[4], y1r3[4][3];
  #pragma unroll
  for (int q = 0; q < 4; q++) {
    int rr = wid * 16 + lq * 4 + q;
    erow[q] = rr;
    esnd[q] = sSnd[rr];
    y0r[q] = sY4[rr][0];
    #pragma unroll
    for (int i = 0; i < 3; i++) y1r3[q][i] = sY4[rr][1 + i];
  }
  float se[4][8];
  #pragma unroll
  for (int q = 0; q < 4; q++)
    #pragma unroll
    for (int nt = 0; nt < 8; nt++)
      se[q][nt] = SU[(size_t)esnd[q] * 128 + nt * 16 + ln];
  float dacc[4][8];

  STAGEB(6)
  __syncthreads();                       // B6

  // ----- cb0 (tile t6) -----
  {
    f32x4 acc3[8];
    #pragma unroll
    for (int nt = 0; nt < 8; nt++) acc3[nt] = (f32x4){0.f, 0.f, 0.f, 0.f};
    GEMM_PASS1(acc3)
    __syncthreads();                     // sB free -> sMsg
    #pragma unroll
    for (int q = 0; q < 4; q++)
      #pragma unroll
      for (int nt = 0; nt < 8; nt++)
        sMsg[erow[q]][nt * 16 + ln] = acc3[nt][q] * se[q][nt] * y0r[q];
    __syncthreads();
    REDUCE(0, -1)
    __syncthreads();
    STAGEB(7)
    __syncthreads();
  }
  // ----- cb1 (tile t7) -----
  {
    f32x4 acc3[8];
    #pragma unroll
    for (int nt = 0; nt < 8; nt++) acc3[nt] = (f32x4){0.f, 0.f, 0.f, 0.f};
    GEMM_PASS1(acc3)
    __syncthreads();
    #pragma unroll
    for (int q = 0; q < 4; q++)
      #pragma unroll
      for (int nt = 0; nt < 8; nt++)
        sMsg[erow[q]][nt * 16 + ln] = acc3[nt][q] * se[q][nt];
    __syncthreads();
    REDUCE3
    __syncthreads();
    STAGEB(8)
    __syncthreads();
  }
  // ----- cb2 (tile t8) -----
  {
    f32x4 acc3[8];
    #pragma unroll
    for (int nt = 0; nt < 8; nt++) acc3[nt] = (f32x4){0.f, 0.f, 0.f, 0.f};
    GEMM_PASS1(acc3)
    __syncthreads();
    for (int pi = 0; pi < 3; pi++) {
      float vu[4][8];
      #pragma unroll
      for (int q = 0; q < 4; q++)
        #pragma unroll
        for (int nt = 0; nt < 8; nt++) {
          vu[q][nt] = VU[(size_t)pi * NP + (size_t)esnd[q] * 128 + nt * 16 + ln];
          if (pi == 0) dacc[q][nt] = vu[q][nt] * y1r3[q][0];
          else dacc[q][nt] += vu[q][nt] * y1r3[q][pi];
        }
      #pragma unroll
      for (int q = 0; q < 4; q++)
        #pragma unroll
        for (int nt = 0; nt < 8; nt++)
          sMsg[erow[q]][nt * 16 + ln] = acc3[nt][q] * vu[q][nt];
      __syncthreads();
      if (pi == 0) { REDUCE(5, 0) }
      else if (pi == 1) { REDUCE(6, 0) }
      else { REDUCE(7, 0) }
      __syncthreads();
    }
    STAGEB(9)
    __syncthreads();
  }
  // ----- cb3 (tile t9) -----
  {
    f32x4 acc3[8];
    #pragma unroll
    for (int nt = 0; nt < 8; nt++) acc3[nt] = (f32x4){0.f, 0.f, 0.f, 0.f};
    GEMM_PASS1(acc3)
    __syncthreads();
    #pragma unroll
    for (int q = 0; q < 4; q++)
      #pragma unroll
      for (int nt = 0; nt < 8; nt++)
        sMsg[erow[q]][nt * 16 + ln] = acc3[nt][q] * dacc[q][nt] * INV_SQRT3C;
    __syncthreads();
    REDUCE(1, -1)
  }
}

// ---------------- fixup: CONT partials + deg-0 zero-fill (no MSG memset) ---
__global__ __launch_bounds__(256) void k_fixup(float* __restrict__ MSG,
                                               const float* __restrict__ CONT,
                                               const int* __restrict__ row_start) {
  int t = blockIdx.x * 256 + threadIdx.x;
  int n = t >> 5;
  int c4 = (t & 31) * 4;
  if (n >= N_NODESC) return;
  int s = row_start[n], e = row_start[n + 1];
  if (e <= s) {
    // degree-0 node: MSG never written by edge kernel -> explicit zeros
    float4 z = {0.f, 0.f, 0.f, 0.f};
    #pragma unroll
    for (int p = 0; p < 8; p++)
      *(float4*)&MSG[(size_t)p * NP + (size_t)n * 128 + c4] = z;
    return;
  }
  int b0 = s >> 6, b1 = (e - 1) >> 6;
  if (b1 <= b0) return;
  for (int p = 0; p < 8; p++) {
    float4 v = *(float4*)&MSG[(size_t)p * NP + (size_t)n * 128 + c4];
    for (int b = b0 + 1; b <= b1; b++) {
      const float4 u = *(const float4*)&CONT[(size_t)b * 1024 + p * 128 + c4];
      v.x += u.x; v.y += u.y; v.z += u.z; v.w += u.w;
    }
    *(float4*)&MSG[(size_t)p * NP + (size_t)n * 128 + c4] = v;
  }
}

// ---------------- K4: output GEMMs (MFMA, A 1-term, 3 blk/CU) --------------
__global__ __launch_bounds__(256, 3) void k_out(
    const float* __restrict__ MSG,
    const ushort* __restrict__ TT,
    float* __restrict__ out)
{
  __shared__ ushort sAh[64][132];
  __shared__ ushort sB[128][132];
  const int n0 = blockIdx.x * 64;
  const int y = blockIdx.y;
  const int cid = threadIdx.x;
  const int wid = cid >> 6;
  const int lane = cid & 63;
  const int lq = lane >> 4;
  const int ln = lane & 15;
  const int ar = wid * 16 + ln;
  const uint4* ttp = (const uint4*)TT;
  const int pA = (y == 0) ? 0 : (1 + y);
  const int pB = (y == 0) ? 1 : (4 + y);
  const int tbase = 16 + ((y == 0) ? 0 : 4);

  f32x4 acc[8];
  #pragma unroll
  for (int nt = 0; nt < 8; nt++) acc[nt] = (f32x4){0.f, 0.f, 0.f, 0.f};

  for (int kh = 0; kh < 2; kh++) {
    if (kh) __syncthreads();             // protect previous PASS reads of sAh
    const int p = kh ? pB : pA;
    for (int idx = cid; idx < 64 * 32; idx += 256) {
      int r = idx >> 5, fc = (idx & 31) << 2;
      int n = n0 + r;
      float4 v = {0.f, 0.f, 0.f, 0.f};
      if (n < N_NODESC) v = *(const float4*)&MSG[(size_t)p * NP + (size_t)n * 128 + fc];
      float vv[4] = {v.x, v.y, v.z, v.w};
      #pragma unroll
      for (int j = 0; j < 4; j++) sAh[r][fc + j] = f2bf_rne(vv[j]);
    }
    STAGEB(tbase + kh * 2)
    __syncthreads();
    GEMM_PASS1(acc)
    __syncthreads();
    STAGEB(tbase + kh * 2 + 1)
    __syncthreads();
    GEMM_PASS1(acc)
  }
  #pragma unroll
  for (int q = 0; q < 4; q++) {
    int n = n0 + wid * 16 + lq * 4 + q;
    if (n < N_NODESC) {
      #pragma unroll
      for (int nt = 0; nt < 8; nt++)
        out[(size_t)n * 512 + (size_t)(nt * 16 + ln) * 4 + y] = acc[nt][q] * SCALE_OUT;
    }
  }
}

extern "C" void kernel_launch(void* const* d_in, const int* in_sizes, int n_in,
                              void* d_out, int out_size, void* d_ws, size_t ws_size,
                              hipStream_t stream) {
  const float* nf  = (const float*)d_in[0];
  const float* ea  = (const float*)d_in[1];
  const float* ef  = (const float*)d_in[2];
  const float* len = (const float*)d_in[3];
  const int*   ei  = (const int*)d_in[4];
  const float* Wsc = (const float*)d_in[5];
  const float* Wu0 = (const float*)d_in[6];
  const float* Wu1 = (const float*)d_in[7];
  const float* W1  = (const float*)d_in[8];
  const float* b1  = (const float*)d_in[9];
  const float* W2  = (const float*)d_in[10];
  const float* b2  = (const float*)d_in[11];
  const float* W3  = (const float*)d_in[12];
  const float* Wo0 = (const float*)d_in[13];
  const float* Wo1 = (const float*)d_in[14];
  float* out = (float*)d_out;
  float* ws  = (float*)d_ws;

  const size_t NPs = (size_t)NP;
  float* P1s  = ws;                            // 1 plane
  float* P1r  = ws + NPs;                      // 1 plane
  float* SU   = ws + 2 * NPs;                  // 1 plane
  float* VU   = ws + 3 * NPs;                  // 3 planes
  float* MSG  = ws + 6 * NPs;                  // 8 planes
  float* CONT = ws + 14 * NPs;                 // NBLK_TOT*1024
  ushort* TT  = (ushort*)(CONT + (size_t)NBLK_TOT * 1024);  // 24*16384 ushorts
  int* perm      = (int*)(TT + 24 * 16384);
  int* deg       = perm + N_EDGESC;
  int* cursor    = deg + N_NODESC;
  int* row_start = cursor + N_NODESC;          // N_NODESC+1 ints

  hipMemsetAsync(deg, 0, N_NODESC * sizeof(int), stream);

  k_histprep<<<1329, 256, 0, stream>>>(ei, deg, W2, W3, Wu0, Wu1, Wo0, Wo1, TT);
  k_scan<<<1, 1024, 0, stream>>>(deg, row_start, cursor);
  k_scatter<<<(N_EDGESC + 255) / 256, 256, 0, stream>>>(ei, row_start, cursor, perm);
  k_wcomp<<<dim3(2, 2), 256, 0, stream>>>(Wsc, W1, TT);

  // y=0..3: node up-projections; y=4: fused per-node perm sort
  k_node_up<<<dim3(157, 5), 256, 0, stream>>>(nf, TT, P1s, P1r, SU, VU,
                                              perm, row_start);

  k_edge_fused<<<NBLK_TOT, 256, 0, stream>>>(P1s, P1r, SU, VU, ef, len, ea, ei,
                                             perm, row_start, W1, b1, b2, TT,
                                             MSG, CONT);

  k_fixup<<<(N_NODESC * 32 + 255) / 256, 256, 0, stream>>>(MSG, CONT, row_start);
  k_out<<<dim3(157, 4), 256, 0, stream>>>(MSG, TT, out);
}